// Round 4
// baseline (4836.551 us; speedup 1.0000x reference)
//
#include <hip/hip_runtime.h>

#define B_ 8
#define C_ 256
#define H_ 64
#define W_ 64
#define HW_ 4096
#define A_ 9
#define SITES 36864      // A_*HW_
#define NPOST 1000
#define XCLIPF 4.1351666f   // (float)4.135166556742356
#define IMGF 1024.0f

// ---------------- K1: 3x3 conv + bias + relu, faithful f32, shift-matmul order ----------------
// acc = sum over (kh,kw) of [sequential fmaf chain over ci]; one thread per (co,pix); ONE batch
__global__ __launch_bounds__(256) void conv3_f32(
    const float* __restrict__ xb, const float* __restrict__ w,
    const float* __restrict__ bias, float* __restrict__ feats) {
#pragma clang fp contract(off)
  int co = blockIdx.x >> 4;                          // [0,256)
  int pix = ((blockIdx.x & 15) << 8) + threadIdx.x;  // [0,4096)
  int h = pix >> 6, wc = pix & 63;
  float acc = 0.f;
  for (int kh = 0; kh < 3; ++kh) {
    int hh = h + kh - 1;
    if ((unsigned)hh >= 64u) continue;
    for (int kw = 0; kw < 3; ++kw) {
      int ww = wc + kw - 1;
      if ((unsigned)ww >= 64u) continue;
      float part = 0.f;
      const float* xp = xb + hh * 64 + ww;
      const float* wp = w + (size_t)co * C_ * 9 + kh * 3 + kw;
      for (int ci = 0; ci < C_; ++ci)
        part = fmaf(wp[ci * 9], xp[(size_t)ci * HW_], part);
      acc = acc + part;   // separate rounding per (kh,kw) partial, kh-major order
    }
  }
  acc = acc + bias[co];
  feats[(size_t)co * HW_ + pix] = acc > 0.f ? acc : 0.f;
}

// ---------------- K2: 1x1 convs (36 box + 9 obj), faithful f32, single ci-chain ----------------
__global__ __launch_bounds__(256) void conv1_f32(
    const float* __restrict__ feats,
    const float* __restrict__ box_w, const float* __restrict__ box_b,
    const float* __restrict__ obj_w, const float* __restrict__ obj_b,
    float* __restrict__ tboxb, float* __restrict__ scoresb) {
#pragma clang fp contract(off)
  int c = blockIdx.x >> 4;                           // [0,45)
  int hw = ((blockIdx.x & 15) << 8) + threadIdx.x;
  const float* wrow = (c < 36) ? (box_w + (size_t)c * C_) : (obj_w + (size_t)(c - 36) * C_);
  float acc = 0.f;
  for (int ci = 0; ci < C_; ++ci)
    acc = fmaf(wrow[ci], feats[(size_t)ci * HW_ + hw], acc);
  if (c < 36) {
    int k = c / 9, a = c - k * 9;
    tboxb[(size_t)k * SITES + (size_t)a * HW_ + hw] = acc + box_b[c];
  } else {
    int a = c - 36;
    scoresb[(size_t)a * HW_ + hw] = acc + obj_b[a];
  }
}

// ---------------- K3: ascending stable rank over all SITES (f32, index tiebreak) ----------------
__global__ __launch_bounds__(256) void rank_sel(
    const float* __restrict__ scores, int* __restrict__ sel_site) {
  int b = blockIdx.x / 144;
  int i = (blockIdx.x % 144) * 256 + threadIdx.x;
  const float* s = scores + (size_t)b * SITES;
  float si = s[i];
  int cnt = 0;
  __shared__ float tile[256];
  for (int t0 = 0; t0 < SITES; t0 += 256) {
    __syncthreads();
    tile[threadIdx.x] = s[t0 + threadIdx.x];
    __syncthreads();
    for (int jj = 0; jj < 256; ++jj) {
      float sj = tile[jj];
      int j = t0 + jj;
      if (sj < si) cnt++;
      else if (sj == si && j < i) cnt++;
    }
  }
  if (cnt < NPOST) sel_site[(size_t)b * NPOST + cnt] = i;
}

// ---------------- K3b: stable descending order over the selected 1000 (f32) ----------------
__global__ __launch_bounds__(1024) void desc_order(
    const float* __restrict__ scores, const int* __restrict__ sel_site,
    int* __restrict__ slot_site, float* __restrict__ s2) {
  int b = blockIdx.x;
  int r = threadIdx.x;
  __shared__ float ss[NPOST];
  if (r < NPOST) ss[r] = scores[(size_t)b * SITES + sel_site[(size_t)b * NPOST + r]];
  __syncthreads();
  if (r < NPOST) {
    float sr = ss[r];
    int d = 0;
    for (int q = 0; q < NPOST; ++q) {
      float sq = ss[q];
      if (sq > sr) d++;
      else if (sq == sr && q < r) d++;
    }
    slot_site[(size_t)b * NPOST + d] = sel_site[(size_t)b * NPOST + r];
    s2[(size_t)b * NPOST + d] = sr;
  }
}

// ---------------- K4: faithful f32 decode of the 1000 slots (separate mul/add, expf) ----------------
__global__ __launch_bounds__(256) void decode_k(
    const float* __restrict__ tbox, const int* __restrict__ slot_site,
    float* __restrict__ b2) {
#pragma clang fp contract(off)
  int idx = blockIdx.x * 256 + threadIdx.x;
  if (idx >= B_ * NPOST) return;
  int b = idx / NPOST, d = idx - b * NPOST;
  int site = slot_site[(size_t)b * NPOST + d];
  int a = site / HW_;
  int hw = site - a * HW_;
  int h = hw / W_, wc = hw - h * W_;
  int sidx = a / 3, ridx = a - sidx * 3;
  float scale = (sidx == 0) ? 128.f : ((sidx == 1) ? 256.f : 512.f);
  float ratio = (ridx == 0) ? 0.5f : ((ridx == 1) ? 1.0f : 2.0f);
  float sq = sqrtf(ratio);
  float wsa = scale / sq;
  float hsa = scale * sq;
  float cx = ((float)wc + 0.5f) * 16.f;
  float cy = ((float)h + 0.5f) * 16.f;
  float ax1 = cx - wsa * 0.5f;   // cx - aw/2
  float ay1 = cy - hsa * 0.5f;
  float ax2 = cx + wsa * 0.5f;
  float ay2 = cy + hsa * 0.5f;
  float aw = ax2 - ax1, ah = ay2 - ay1;
  float m1 = 0.5f * aw, m2 = 0.5f * ah;
  float acx = ax1 + m1, acy = ay1 + m2;
  const float* tb = tbox + (size_t)b * 4 * SITES + site;
  float t0 = tb[0];
  float t1 = tb[SITES];
  float t2 = tb[2 * (size_t)SITES];
  float t3 = tb[3 * (size_t)SITES];
  if (t2 < -XCLIPF) t2 = -XCLIPF;
  if (t2 > XCLIPF) t2 = XCLIPF;
  if (t3 < -XCLIPF) t3 = -XCLIPF;
  if (t3 > XCLIPF) t3 = XCLIPF;
  float pm0 = t0 * aw;  float pcx = pm0 + acx;
  float pm1 = t1 * ah;  float pcy = pm1 + acy;
  float pw = expf(t2) * aw;
  float ph = expf(t3) * ah;
  float hw0 = 0.5f * pw, hh0 = 0.5f * ph;
  float x1 = pcx - hw0, y1 = pcy - hh0;
  float x2 = pcx + hw0, y2 = pcy + hh0;
  x1 = x1 < 0.f ? 0.f : (x1 > IMGF ? IMGF : x1);
  y1 = y1 < 0.f ? 0.f : (y1 > IMGF ? IMGF : y1);
  x2 = x2 < 0.f ? 0.f : (x2 > IMGF ? IMGF : x2);
  y2 = y2 < 0.f ? 0.f : (y2 > IMGF ? IMGF : y2);
  float* o = b2 + ((size_t)b * NPOST + d) * 4;
  o[0] = x1; o[1] = y1; o[2] = x2; o[3] = y2;
}

// ---------------- K5: literal fori_loop NMS (f32 IoU) + compaction + zero fill ----------------
__global__ __launch_bounds__(1024) void nms_compact(
    const float* __restrict__ b2, const float* __restrict__ s2,
    float* __restrict__ out) {
#pragma clang fp contract(off)
  int b = blockIdx.x;
  int j = threadIdx.x;
  __shared__ float bx[NPOST * 4];
  __shared__ float ar[NPOST];
  __shared__ int keep[NPOST];
  if (j < NPOST) {
    const float* src = b2 + ((size_t)b * NPOST + j) * 4;
    bx[j * 4 + 0] = src[0];
    bx[j * 4 + 1] = src[1];
    bx[j * 4 + 2] = src[2];
    bx[j * 4 + 3] = src[3];
    ar[j] = (src[2] - src[0]) * (src[3] - src[1]);
    keep[j] = 1;
  }
  __syncthreads();
  float jx1 = 0, jy1 = 0, jx2 = 0, jy2 = 0, ja = 0;
  if (j < NPOST) {
    jx1 = bx[j * 4 + 0]; jy1 = bx[j * 4 + 1];
    jx2 = bx[j * 4 + 2]; jy2 = bx[j * 4 + 3];
    ja = ar[j];
  }
  for (int i = 0; i < NPOST; ++i) {
    int ki = keep[i];  // row i never written during iteration i (writes target j>i)
    if (ki && j > i && j < NPOST) {
      float lx = fmaxf(bx[i * 4 + 0], jx1);
      float ly = fmaxf(bx[i * 4 + 1], jy1);
      float rx = fminf(bx[i * 4 + 2], jx2);
      float ry = fminf(bx[i * 4 + 3], jy2);
      float iw = rx - lx; if (iw < 0.f) iw = 0.f;
      float ih = ry - ly; if (ih < 0.f) ih = 0.f;
      float inter = iw * ih;
      float denom = (ar[i] + ja) - inter;
      float iou = inter / denom;
      if (iou > 0.7f) keep[j] = 0;
    }
    __syncthreads();
  }
  if (j < NPOST) {
    int total = 0;
    for (int q = 0; q < NPOST; ++q) total += keep[q];
    int before = 0;
    for (int q = 0; q < j; ++q) before += keep[q];
    if (keep[j]) {
      size_t ob = (size_t)b * (NPOST * 5) + (size_t)before * 5;
      out[ob + 0] = jx1;
      out[ob + 1] = jy1;
      out[ob + 2] = jx2;
      out[ob + 3] = jy2;
      out[ob + 4] = s2[(size_t)b * NPOST + j];
    }
    if (j >= total) {
      size_t ob = (size_t)b * (NPOST * 5) + (size_t)j * 5;
      for (int c = 0; c < 5; ++c) out[ob + c] = 0.f;
    }
  }
}

extern "C" void kernel_launch(void* const* d_in, const int* in_sizes, int n_in,
                              void* d_out, int out_size, void* d_ws, size_t ws_size,
                              hipStream_t stream) {
  // Map inputs by unique flat size (insurance against ordering surprises)
  const float *x = nullptr, *conv_w = nullptr, *conv_b = nullptr,
              *box_w = nullptr, *box_b = nullptr, *obj_w = nullptr, *obj_b = nullptr;
  for (int i = 0; i < n_in; ++i) {
    switch (in_sizes[i]) {
      case 8388608: x = (const float*)d_in[i]; break;      // 8*256*64*64
      case 589824:  conv_w = (const float*)d_in[i]; break; // 256*256*9
      case 256:     conv_b = (const float*)d_in[i]; break;
      case 9216:    box_w = (const float*)d_in[i]; break;  // 36*256
      case 36:      box_b = (const float*)d_in[i]; break;
      case 2304:    obj_w = (const float*)d_in[i]; break;  // 9*256
      case 9:       obj_b = (const float*)d_in[i]; break;
    }
  }
  float* out = (float*)d_out;

  // Workspace (~11 MB), feats staged one batch at a time
  char* p = (char*)d_ws;
  auto alloc = [&](size_t n) { char* q = p; p += (n + 255) & ~255ull; return (void*)q; };
  float* feats1 = (float*)alloc((size_t)C_ * HW_ * 4);            // 4.19 MB
  float* tbox   = (float*)alloc((size_t)B_ * 4 * SITES * 4);      // 4.72 MB
  float* scores = (float*)alloc((size_t)B_ * SITES * 4);          // 1.18 MB
  int* sel_site  = (int*)alloc((size_t)B_ * NPOST * 4);
  int* slot_site = (int*)alloc((size_t)B_ * NPOST * 4);
  float* s2      = (float*)alloc((size_t)B_ * NPOST * 4);
  float* b2      = (float*)alloc((size_t)B_ * NPOST * 4 * 4);

  for (int b = 0; b < B_; ++b) {
    hipLaunchKernelGGL(conv3_f32, dim3(C_ * 16), dim3(256), 0, stream,
                       x + (size_t)b * C_ * HW_, conv_w, conv_b, feats1);
    hipLaunchKernelGGL(conv1_f32, dim3(45 * 16), dim3(256), 0, stream,
                       feats1, box_w, box_b, obj_w, obj_b,
                       tbox + (size_t)b * 4 * SITES, scores + (size_t)b * SITES);
  }
  hipLaunchKernelGGL(rank_sel, dim3(B_ * 144), dim3(256), 0, stream, scores, sel_site);
  hipLaunchKernelGGL(desc_order, dim3(B_), dim3(1024), 0, stream,
                     scores, sel_site, slot_site, s2);
  hipLaunchKernelGGL(decode_k, dim3((B_ * NPOST + 255) / 256), dim3(256), 0, stream,
                     tbox, slot_site, b2);
  hipLaunchKernelGGL(nms_compact, dim3(B_), dim3(1024), 0, stream, b2, s2, out);
}